// Round 1
// 3087.250 us; speedup vs baseline: 1.6869x; 1.6869x over previous
//
#include <hip/hip_runtime.h>
#include <hip/hip_bf16.h>

#define H_DIM 2048
#define I_DIM 5632
#define E_NUM 8
#define T_NUM 2048
#define BK 32

// ---- workspace layout (bytes) ----
static constexpr size_t WS_COUNTS  = 0;
static constexpr size_t WS_CURSORS = 64;
static constexpr size_t WS_OFFSETS = 128;
static constexpr size_t WS_ROWTOK  = 256;
static constexpr size_t WS_ROWWT   = WS_ROWTOK + 4096 * 4;
static constexpr size_t WS_TOKROWS = WS_ROWWT + 4096 * 4;
static constexpr size_t WS_TOKWTS  = WS_TOKROWS + T_NUM * 2 * 4;
static constexpr size_t WS_ACT     = 1u << 20;
static constexpr size_t WS_Y       = WS_ACT + (size_t)4096 * I_DIM * 2;
// fast-path extras:
static constexpr size_t WS_XB      = WS_Y + (size_t)4096 * H_DIM * 4;               // x as bf16 [T][H]
static constexpr size_t WS_WG      = WS_XB + (size_t)T_NUM * H_DIM * 2;             // w_gate bf16 tiled
static constexpr size_t WS_WU      = WS_WG + (size_t)E_NUM * I_DIM * H_DIM * 2;     // w_up bf16 tiled
static constexpr size_t WS_WD      = WS_WU + (size_t)E_NUM * I_DIM * H_DIM * 2;     // w_down bf16 tiled
static constexpr size_t WS_NEED_FAST = WS_WD + (size_t)E_NUM * H_DIM * I_DIM * 2;

typedef __attribute__((ext_vector_type(8))) short short8;
typedef __attribute__((ext_vector_type(4))) float f32x4;

__device__ __forceinline__ ushort f2bf(float f) {
    union { float f; unsigned int u; } v; v.f = f;
    return (ushort)((v.u + 0x8000u) >> 16);
}

// async global->LDS, 16B per lane. Global src is PER-LANE; LDS dest is wave-uniform base + lane*16.
__device__ __forceinline__ void gload16(const void* g, void* l) {
    __builtin_amdgcn_global_load_lds((const __attribute__((address_space(1))) void*)g,
                                     (__attribute__((address_space(3))) void*)l, 16, 0, 0);
}

// ---------------- router: one wave per token ----------------
__global__ __launch_bounds__(256) void router_kernel(
    const float* __restrict__ x, const float* __restrict__ gw,
    int* __restrict__ counts, int* __restrict__ tok_e, float* __restrict__ tok_w)
{
    int wid = threadIdx.x >> 6, lane = threadIdx.x & 63;
    int t = blockIdx.x * 4 + wid;
    const float* xr = x + (size_t)t * H_DIM;
    float acc[E_NUM];
#pragma unroll
    for (int e = 0; e < E_NUM; ++e) acc[e] = 0.f;
    for (int h = lane; h < H_DIM; h += 64) {
        float xv = xr[h];
#pragma unroll
        for (int e = 0; e < E_NUM; ++e) acc[e] += xv * gw[e * H_DIM + h];
    }
#pragma unroll
    for (int e = 0; e < E_NUM; ++e)
        for (int o = 32; o > 0; o >>= 1) acc[e] += __shfl_down(acc[e], o);
    if (lane == 0) {
        int e0 = 0; float l0 = acc[0];
#pragma unroll
        for (int e = 1; e < E_NUM; ++e) if (acc[e] > l0) { l0 = acc[e]; e0 = e; }
        int e1 = -1; float l1 = -1e30f;
#pragma unroll
        for (int e = 0; e < E_NUM; ++e) if (e != e0 && acc[e] > l1) { l1 = acc[e]; e1 = e; }
        float p1 = __expf(l1 - l0);
        float inv = 1.f / (1.f + p1);
        atomicAdd(&counts[e0], 1);
        atomicAdd(&counts[e1], 1);
        tok_e[2 * t] = e0; tok_e[2 * t + 1] = e1;
        tok_w[2 * t] = inv; tok_w[2 * t + 1] = p1 * inv;
    }
}

__global__ void scan_kernel(const int* __restrict__ counts, int* __restrict__ offsets) {
    if (threadIdx.x == 0) {
        int s = 0;
#pragma unroll
        for (int e = 0; e < E_NUM; ++e) { offsets[e] = s; s += counts[e]; }
        offsets[E_NUM] = s;
    }
}

__global__ __launch_bounds__(256) void assign_kernel(
    const int* __restrict__ offsets, int* __restrict__ cursors,
    int* __restrict__ tok_rows, const float* __restrict__ tok_w,
    int* __restrict__ rows_tok, float* __restrict__ rows_wt)
{
    int t = blockIdx.x * 256 + threadIdx.x;
#pragma unroll
    for (int j = 0; j < 2; ++j) {
        int e = tok_rows[2 * t + j];
        int slot = atomicAdd(&cursors[e], 1);
        int row = offsets[e] + slot;
        rows_tok[row] = t;
        rows_wt[row] = tok_w[2 * t + j];
        tok_rows[2 * t + j] = row;
    }
}

// ---------------- x fp32 -> bf16 (row-major copy) ----------------
__global__ __launch_bounds__(256) void xconv_kernel(const float* __restrict__ x, ushort* __restrict__ xb) {
    int i = (blockIdx.x * 256 + threadIdx.x) * 8;
    float4 a = *(const float4*)(x + i), b = *(const float4*)(x + i + 4);
    ushort4 o0 = make_ushort4(f2bf(a.x), f2bf(a.y), f2bf(a.z), f2bf(a.w));
    ushort4 o1 = make_ushort4(f2bf(b.x), f2bf(b.y), f2bf(b.z), f2bf(b.w));
    *(ushort4*)(xb + i) = o0; *(ushort4*)(xb + i + 4) = o1;
}

// ---------------- weight retile: fp32 [E][R][K] -> bf16 K-step tiles ----------------
// dst tile index ((e*Y + y)*S + s); tile = 128 rows x 32 k = 8KB, bank-swizzled:
// 16B-chunk for (row rl, logical quad q) at c16 = rl*4 + (q ^ ((rl>>1)&3)).
// Each block handles 128 rows x 128 k; reads rows contiguously, writes tiles contiguously.
__global__ __launch_bounds__(256) void retile_kernel(
    const float* __restrict__ src, ushort* __restrict__ dst, const int K)
{
    const int sg = blockIdx.x, y = blockIdx.y, e = blockIdx.z;
    const int R = gridDim.y * 128;     // rows per expert
    const int S = gridDim.x * 4;       // k-steps per row
    __shared__ __align__(16) ushort tile[4 * 4096];   // 4 steps x 8KB = 32KB
    const int t = threadIdx.x;
    const int rl = t >> 1, half = t & 1;
    const float* srow = src + ((size_t)e * R + (size_t)y * 128 + rl) * K + sg * 128 + half * 64;
    const int f = (rl >> 1) & 3;
#pragma unroll
    for (int c = 0; c < 8; ++c) {
        float4 v0 = *(const float4*)(srow + c * 8);
        float4 v1 = *(const float4*)(srow + c * 8 + 4);
        int k = half * 64 + c * 8;
        int st = k >> 5;
        int q = (k >> 3) & 3;
        ushort* p = &tile[st * 4096 + (rl * 4 + (q ^ f)) * 8];
        p[0] = f2bf(v0.x); p[1] = f2bf(v0.y); p[2] = f2bf(v0.z); p[3] = f2bf(v0.w);
        p[4] = f2bf(v1.x); p[5] = f2bf(v1.y); p[6] = f2bf(v1.z); p[7] = f2bf(v1.w);
    }
    __syncthreads();
    const uint4* ldp = (const uint4*)tile;
    uint4* stp = (uint4*)(dst + ((size_t)(e * gridDim.y + y) * S + (size_t)sg * 4) * 4096);
#pragma unroll
    for (int i = 0; i < 8; ++i) stp[t + i * 256] = ldp[t + i * 256];
}

// ---------------- fast gemm1: bf16, global_load_lds staging, swizzled LDS ----------------
__global__ __launch_bounds__(256) void gemm1f_kernel(
    const ushort* __restrict__ xb, const ushort* __restrict__ wgt, const ushort* __restrict__ wut,
    const int* __restrict__ offsets, const int* __restrict__ rows_tok, ushort* __restrict__ act)
{
    const int e = blockIdx.z;
    const int off = offsets[e];
    const int ne = offsets[e + 1] - off;
    const int row0 = blockIdx.x * 128;
    if (row0 >= ne) return;
    const int col0 = blockIdx.y * 128;

    __shared__ __align__(16) ushort sA[4096];
    __shared__ __align__(16) ushort sBg[4096];
    __shared__ __align__(16) ushort sBu[4096];

    const int tid = threadIdx.x;
    const int lane = tid & 63, wid = tid >> 6;
    const int wm = wid & 1, wn = wid >> 1;
    const int quad = lane >> 4, l16 = lane & 15;
    const int chunk0 = wid * 2;           // this wave stages 1KB-issues {chunk0, chunk0+1} of 8

    // B tile streams for this (e, col-block): 8KB contiguous per K-step
    const ushort* bg = wgt + (size_t)(e * 44 + blockIdx.y) * 64 * 4096;
    const ushort* bu = wut + (size_t)(e * 44 + blockIdx.y) * 64 * 4096;

    // A gather: per-lane pre-swizzled source pointers for 2 issues (16 rows each)
    const int qp = lane & 3;
    const ushort* pA[2];
#pragma unroll
    for (int ii = 0; ii < 2; ++ii) {
        int rl = (chunk0 + ii) * 16 + (lane >> 2);
        int gr = row0 + rl;
        int tok = (gr < ne) ? rows_tok[off + gr] : 0;
        int q = qp ^ ((rl >> 1) & 3);
        pA[ii] = xb + (size_t)tok * H_DIM + q * 8;
    }

    f32x4 accg[4][4], accu[4][4];
#pragma unroll
    for (int i = 0; i < 4; ++i)
#pragma unroll
        for (int j = 0; j < 4; ++j) { accg[i][j] = (f32x4){0.f,0.f,0.f,0.f}; accu[i][j] = (f32x4){0.f,0.f,0.f,0.f}; }

    for (int s = 0; s < 64; ++s) {
        __syncthreads();
        const ushort* bgs = bg + (size_t)s * 4096;
        const ushort* bus = bu + (size_t)s * 4096;
#pragma unroll
        for (int ii = 0; ii < 2; ++ii) {
            gload16(pA[ii] + s * 32,                      (char*)sA  + (chunk0 + ii) * 1024);
            gload16(bgs + (chunk0 + ii) * 512 + lane * 8, (char*)sBg + (chunk0 + ii) * 1024);
            gload16(bus + (chunk0 + ii) * 512 + lane * 8, (char*)sBu + (chunk0 + ii) * 1024);
        }
        __syncthreads();

        short8 af[4], bgf[4], buf_[4];
#pragma unroll
        for (int i = 0; i < 4; ++i) {
            int ra = wm * 64 + i * 16 + l16;
            int rb = wn * 64 + i * 16 + l16;
            af[i]   = *(const short8*)&sA [(ra * 4 + (quad ^ ((ra >> 1) & 3))) * 8];
            bgf[i]  = *(const short8*)&sBg[(rb * 4 + (quad ^ ((rb >> 1) & 3))) * 8];
            buf_[i] = *(const short8*)&sBu[(rb * 4 + (quad ^ ((rb >> 1) & 3))) * 8];
        }
#pragma unroll
        for (int i = 0; i < 4; ++i)
#pragma unroll
            for (int j = 0; j < 4; ++j) {
                accg[i][j] = __builtin_amdgcn_mfma_f32_16x16x32_bf16(af[i], bgf[j], accg[i][j], 0, 0, 0);
                accu[i][j] = __builtin_amdgcn_mfma_f32_16x16x32_bf16(af[i], buf_[j], accu[i][j], 0, 0, 0);
            }
    }

#pragma unroll
    for (int i = 0; i < 4; ++i) {
#pragma unroll
        for (int reg = 0; reg < 4; ++reg) {
            int lr = wm * 64 + i * 16 + quad * 4 + reg;
            int r = row0 + lr;
            if (r < ne) {
                size_t base = (size_t)(off + r) * I_DIM + col0 + wn * 64;
#pragma unroll
                for (int j = 0; j < 4; ++j) {
                    float g = accg[i][j][reg], u = accu[i][j][reg];
                    float a = g * (1.f / (1.f + __expf(-g))) * u;
                    act[base + j * 16 + l16] = f2bf(a);
                }
            }
        }
    }
}

// ---------------- fast gemm2: bf16, global_load_lds staging ----------------
__global__ __launch_bounds__(256) void gemm2f_kernel(
    const ushort* __restrict__ act, const ushort* __restrict__ wdt,
    const int* __restrict__ offsets, const float* __restrict__ rows_wt, float* __restrict__ y)
{
    const int e = blockIdx.z;
    const int off = offsets[e];
    const int ne = offsets[e + 1] - off;
    const int row0 = blockIdx.x * 128;
    if (row0 >= ne) return;
    const int col0 = blockIdx.y * 128;

    __shared__ __align__(16) ushort sA[4096];
    __shared__ __align__(16) ushort sB[4096];
    __shared__ float sWt[128];

    const int tid = threadIdx.x;
    const int lane = tid & 63, wid = tid >> 6;
    const int wm = wid & 1, wn = wid >> 1;
    const int quad = lane >> 4, l16 = lane & 15;
    const int chunk0 = wid * 2;

    if (tid < 128) sWt[tid] = (row0 + tid < ne) ? rows_wt[off + row0 + tid] : 0.f;

    const ushort* bd = wdt + (size_t)(e * 16 + blockIdx.y) * 176 * 4096;

    const int qp = lane & 3;
    const ushort* pA[2];
#pragma unroll
    for (int ii = 0; ii < 2; ++ii) {
        int rl = (chunk0 + ii) * 16 + (lane >> 2);
        int gr = off + row0 + rl; if (gr > 4095) gr = 4095;
        int q = qp ^ ((rl >> 1) & 3);
        pA[ii] = act + (size_t)gr * I_DIM + q * 8;
    }

    f32x4 acc[4][4];
#pragma unroll
    for (int i = 0; i < 4; ++i)
#pragma unroll
        for (int j = 0; j < 4; ++j) acc[i][j] = (f32x4){0.f,0.f,0.f,0.f};

    for (int s = 0; s < 176; ++s) {
        __syncthreads();
        const ushort* bds = bd + (size_t)s * 4096;
#pragma unroll
        for (int ii = 0; ii < 2; ++ii) {
            gload16(pA[ii] + s * 32,                      (char*)sA + (chunk0 + ii) * 1024);
            gload16(bds + (chunk0 + ii) * 512 + lane * 8, (char*)sB + (chunk0 + ii) * 1024);
        }
        __syncthreads();

        short8 af[4], bf[4];
#pragma unroll
        for (int i = 0; i < 4; ++i) {
            int ra = wm * 64 + i * 16 + l16;
            int rb = wn * 64 + i * 16 + l16;
            af[i] = *(const short8*)&sA[(ra * 4 + (quad ^ ((ra >> 1) & 3))) * 8];
            bf[i] = *(const short8*)&sB[(rb * 4 + (quad ^ ((rb >> 1) & 3))) * 8];
        }
#pragma unroll
        for (int i = 0; i < 4; ++i)
#pragma unroll
            for (int j = 0; j < 4; ++j)
                acc[i][j] = __builtin_amdgcn_mfma_f32_16x16x32_bf16(af[i], bf[j], acc[i][j], 0, 0, 0);
    }

#pragma unroll
    for (int i = 0; i < 4; ++i) {
#pragma unroll
        for (int reg = 0; reg < 4; ++reg) {
            int lr = wm * 64 + i * 16 + quad * 4 + reg;
            int r = row0 + lr;
            if (r < ne) {
                float wt = sWt[lr];
                size_t base = (size_t)(off + r) * H_DIM + col0 + wn * 64;
#pragma unroll
                for (int j = 0; j < 4; ++j)
                    y[base + j * 16 + l16] = wt * acc[i][j][reg];
            }
        }
    }
}

// ================= fallback (previous verified path) =================
__global__ __launch_bounds__(256) void gemm1_kernel(
    const float* __restrict__ x, const float* __restrict__ w_gate, const float* __restrict__ w_up,
    const int* __restrict__ offsets, const int* __restrict__ rows_tok, ushort* __restrict__ act)
{
    const int e = blockIdx.z;
    const int off = offsets[e];
    const int ne = offsets[e + 1] - off;
    const int row0 = blockIdx.x * 128;
    if (row0 >= ne) return;
    const int col0 = blockIdx.y * 128;

    __shared__ __align__(16) ushort sA[128 * 56];
    __shared__ __align__(16) ushort sBg[128 * 56];
    __shared__ __align__(16) ushort sBu[128 * 56];

    const int tid = threadIdx.x;
    const int lane = tid & 63, wid = tid >> 6;
    const int wm = wid & 1, wn = wid >> 1;
    const int quad = lane >> 4, l16 = lane & 15;
    const int srow = tid >> 3, skc = tid & 7;

    int tokid[4];
#pragma unroll
    for (int rb = 0; rb < 4; ++rb) {
        int gr = row0 + rb * 32 + srow;
        tokid[rb] = (gr < ne) ? rows_tok[off + gr] : -1;
    }

    const float* wg = w_gate + (size_t)e * I_DIM * H_DIM;
    const float* wu = w_up   + (size_t)e * I_DIM * H_DIM;

    f32x4 accg[4][4], accu[4][4];
#pragma unroll
    for (int i = 0; i < 4; ++i)
#pragma unroll
        for (int j = 0; j < 4; ++j) { accg[i][j] = (f32x4){0.f,0.f,0.f,0.f}; accu[i][j] = (f32x4){0.f,0.f,0.f,0.f}; }

    for (int kk = 0; kk < H_DIM; kk += BK) {
        __syncthreads();
#pragma unroll
        for (int rb = 0; rb < 4; ++rb) {
            int r = rb * 32 + srow;
            ushort4 w;
            if (tokid[rb] >= 0) {
                const float4 v = *(const float4*)(x + (size_t)tokid[rb] * H_DIM + kk + skc * 4);
                w = make_ushort4(f2bf(v.x), f2bf(v.y), f2bf(v.z), f2bf(v.w));
            } else w = make_ushort4(0, 0, 0, 0);
            *(ushort4*)&sA[r * 56 + skc * 4] = w;
        }
#pragma unroll
        for (int rb = 0; rb < 4; ++rb) {
            int r = rb * 32 + srow;
            size_t go = (size_t)(col0 + r) * H_DIM + kk + skc * 4;
            const float4 vg = *(const float4*)(wg + go);
            const float4 vu = *(const float4*)(wu + go);
            *(ushort4*)&sBg[r * 56 + skc * 4] = make_ushort4(f2bf(vg.x), f2bf(vg.y), f2bf(vg.z), f2bf(vg.w));
            *(ushort4*)&sBu[r * 56 + skc * 4] = make_ushort4(f2bf(vu.x), f2bf(vu.y), f2bf(vu.z), f2bf(vu.w));
        }
        __syncthreads();

        short8 af[4], bgf[4], buf_[4];
#pragma unroll
        for (int i = 0; i < 4; ++i) {
            af[i]   = *(const short8*)&sA [(wm * 64 + i * 16 + l16) * 56 + quad * 8];
            bgf[i]  = *(const short8*)&sBg[(wn * 64 + i * 16 + l16) * 56 + quad * 8];
            buf_[i] = *(const short8*)&sBu[(wn * 64 + i * 16 + l16) * 56 + quad * 8];
        }
#pragma unroll
        for (int i = 0; i < 4; ++i)
#pragma unroll
            for (int j = 0; j < 4; ++j) {
                accg[i][j] = __builtin_amdgcn_mfma_f32_16x16x32_bf16(af[i], bgf[j], accg[i][j], 0, 0, 0);
                accu[i][j] = __builtin_amdgcn_mfma_f32_16x16x32_bf16(af[i], buf_[j], accu[i][j], 0, 0, 0);
            }
    }

#pragma unroll
    for (int i = 0; i < 4; ++i) {
#pragma unroll
        for (int reg = 0; reg < 4; ++reg) {
            int lr = wm * 64 + i * 16 + quad * 4 + reg;
            int r = row0 + lr;
            if (r < ne) {
                size_t base = (size_t)(off + r) * I_DIM + col0 + wn * 64;
#pragma unroll
                for (int j = 0; j < 4; ++j) {
                    float g = accg[i][j][reg], u = accu[i][j][reg];
                    float a = g * (1.f / (1.f + __expf(-g))) * u;
                    act[base + j * 16 + l16] = f2bf(a);
                }
            }
        }
    }
}

__global__ __launch_bounds__(256) void gemm2_kernel(
    const ushort* __restrict__ act, const float* __restrict__ w_down,
    const int* __restrict__ offsets, const float* __restrict__ rows_wt, float* __restrict__ y)
{
    const int e = blockIdx.z;
    const int off = offsets[e];
    const int ne = offsets[e + 1] - off;
    const int row0 = blockIdx.x * 128;
    if (row0 >= ne) return;
    const int col0 = blockIdx.y * 128;

    __shared__ __align__(16) ushort sA[128 * 56];
    __shared__ __align__(16) ushort sB[128 * 56];
    __shared__ float sWt[128];

    const int tid = threadIdx.x;
    const int lane = tid & 63, wid = tid >> 6;
    const int wm = wid & 1, wn = wid >> 1;
    const int quad = lane >> 4, l16 = lane & 15;

    if (tid < 128) sWt[tid] = (row0 + tid < ne) ? rows_wt[off + row0 + tid] : 0.f;

    const float* wd = w_down + (size_t)e * H_DIM * I_DIM;

    f32x4 acc[4][4];
#pragma unroll
    for (int i = 0; i < 4; ++i)
#pragma unroll
        for (int j = 0; j < 4; ++j) acc[i][j] = (f32x4){0.f,0.f,0.f,0.f};

    const int arow = tid >> 2, akc = tid & 3;
    const int brow = tid >> 3, bkc = tid & 7;

    for (int kk = 0; kk < I_DIM; kk += BK) {
        __syncthreads();
#pragma unroll
        for (int rb = 0; rb < 2; ++rb) {
            int r = rb * 64 + arow;
            int gr = row0 + r;
            uint4 v = make_uint4(0, 0, 0, 0);
            if (gr < ne) v = *(const uint4*)(act + (size_t)(off + gr) * I_DIM + kk + akc * 8);
            *(uint4*)&sA[r * 56 + akc * 8] = v;
        }
#pragma unroll
        for (int rb = 0; rb < 4; ++rb) {
            int r = rb * 32 + brow;
            const float4 v = *(const float4*)(wd + (size_t)(col0 + r) * I_DIM + kk + bkc * 4);
            *(ushort4*)&sB[r * 56 + bkc * 4] = make_ushort4(f2bf(v.x), f2bf(v.y), f2bf(v.z), f2bf(v.w));
        }
        __syncthreads();

        short8 af[4], bf[4];
#pragma unroll
        for (int i = 0; i < 4; ++i) {
            af[i] = *(const short8*)&sA[(wm * 64 + i * 16 + l16) * 56 + quad * 8];
            bf[i] = *(const short8*)&sB[(wn * 64 + i * 16 + l16) * 56 + quad * 8];
        }
#pragma unroll
        for (int i = 0; i < 4; ++i)
#pragma unroll
            for (int j = 0; j < 4; ++j)
                acc[i][j] = __builtin_amdgcn_mfma_f32_16x16x32_bf16(af[i], bf[j], acc[i][j], 0, 0, 0);
    }

#pragma unroll
    for (int i = 0; i < 4; ++i) {
#pragma unroll
        for (int reg = 0; reg < 4; ++reg) {
            int lr = wm * 64 + i * 16 + quad * 4 + reg;
            int r = row0 + lr;
            if (r < ne) {
                float wt = sWt[lr];
                size_t base = (size_t)(off + r) * H_DIM + col0 + wn * 64;
#pragma unroll
                for (int j = 0; j < 4; ++j)
                    y[base + j * 16 + l16] = wt * acc[i][j][reg];
            }
        }
    }
}

// ---------------- combine ----------------
__global__ __launch_bounds__(256) void combine_kernel(
    const float* __restrict__ y, const int* __restrict__ tok_rows, float* __restrict__ out)
{
    int idx = blockIdx.x * 256 + threadIdx.x;
    int t = idx >> 9;
    int c = idx & 511;
    int r0 = tok_rows[2 * t], r1 = tok_rows[2 * t + 1];
    const float4 a = *(const float4*)(y + (size_t)r0 * H_DIM + c * 4);
    const float4 b = *(const float4*)(y + (size_t)r1 * H_DIM + c * 4);
    float4 o; o.x = a.x + b.x; o.y = a.y + b.y; o.z = a.z + b.z; o.w = a.w + b.w;
    *(float4*)(out + (size_t)t * H_DIM + c * 4) = o;
}

extern "C" void kernel_launch(void* const* d_in, const int* in_sizes, int n_in,
                              void* d_out, int out_size, void* d_ws, size_t ws_size,
                              hipStream_t stream) {
    const float* x      = (const float*)d_in[0];
    const float* gate_w = (const float*)d_in[1];
    const float* w_gate = (const float*)d_in[2];
    const float* w_up   = (const float*)d_in[3];
    const float* w_down = (const float*)d_in[4];
    float* out = (float*)d_out;
    char* ws = (char*)d_ws;

    int*    counts   = (int*)(ws + WS_COUNTS);
    int*    cursors  = (int*)(ws + WS_CURSORS);
    int*    offsets  = (int*)(ws + WS_OFFSETS);
    int*    rows_tok = (int*)(ws + WS_ROWTOK);
    float*  rows_wt  = (float*)(ws + WS_ROWWT);
    int*    tok_rows = (int*)(ws + WS_TOKROWS);
    float*  tok_wts  = (float*)(ws + WS_TOKWTS);
    ushort* act      = (ushort*)(ws + WS_ACT);
    float*  y        = (float*)(ws + WS_Y);

    hipMemsetAsync(ws, 0, 256, stream);
    router_kernel<<<T_NUM / 4, 256, 0, stream>>>(x, gate_w, counts, tok_rows, tok_wts);
    scan_kernel<<<1, 64, 0, stream>>>(counts, offsets);
    assign_kernel<<<T_NUM / 256, 256, 0, stream>>>(offsets, cursors, tok_rows, tok_wts, rows_tok, rows_wt);

    if (ws_size >= WS_NEED_FAST) {
        ushort* xb  = (ushort*)(ws + WS_XB);
        ushort* wgt = (ushort*)(ws + WS_WG);
        ushort* wut = (ushort*)(ws + WS_WU);
        ushort* wdt = (ushort*)(ws + WS_WD);
        xconv_kernel<<<T_NUM * H_DIM / 8 / 256, 256, 0, stream>>>(x, xb);
        retile_kernel<<<dim3(16, 44, E_NUM), 256, 0, stream>>>(w_gate, wgt, H_DIM);
        retile_kernel<<<dim3(16, 44, E_NUM), 256, 0, stream>>>(w_up,   wut, H_DIM);
        retile_kernel<<<dim3(44, 16, E_NUM), 256, 0, stream>>>(w_down, wdt, I_DIM);
        gemm1f_kernel<<<dim3(16, I_DIM / 128, E_NUM), 256, 0, stream>>>(xb, wgt, wut, offsets, rows_tok, act);
        gemm2f_kernel<<<dim3(16, H_DIM / 128, E_NUM), 256, 0, stream>>>(act, wdt, offsets, rows_wt, y);
    } else {
        gemm1_kernel<<<dim3(16, I_DIM / 128, E_NUM), 256, 0, stream>>>(x, w_gate, w_up, offsets, rows_tok, act);
        gemm2_kernel<<<dim3(16, H_DIM / 128, E_NUM), 256, 0, stream>>>(act, w_down, offsets, rows_wt, y);
    }
    combine_kernel<<<(T_NUM * H_DIM / 4) / 256, 256, 0, stream>>>(y, tok_rows, out);
}